// Round 4
// baseline (491.645 us; speedup 1.0000x reference)
//
#include <hip/hip_runtime.h>
#include <hip/hip_bf16.h>

// NonlinearReservoirCell: B=262144 rows, M=3 independent tiny MLPs
//   free_water = last_free_water + sum_n runoff
//   a1 = relu(runoff @ W1 + b1)   (256 -> 256)
//   a2 = relu(a1 @ W2 + b2)       (256 -> 128)
//   ratio = sigmoid(a2 @ W3 + b3) (128 -> 1)
//   flow = fw*ratio + last_flow*(1-ratio);  new_fw = fw - flow
// bf16 MFMA (32x32x16), batch row = lane&31 (swapped orientation).
// R4: DRAM-order fix. Runoff is register-staged per wave as 32x 1-KB
//     contiguous bursts (was: 128-B granules at 3-KB stride = 2.8 TB/s eff),
//     then cvt->bf16 into per-wave swizzled LDS panels. XCD swizzle puts the
//     3 m-partner blocks of a row range on one XCD so their streams merge.
//     W2 LDS-resident; W1 ring-3 of 1-kk panels, one barrier + vmcnt(2)/kk.

#define B_TOT 262144
#define M_    3
#define N_    256
#define H1_   256
#define H2_   128
#define BM_   (B_TOT * M_)

typedef __bf16 bf16_t;
typedef __bf16  bf16x8 __attribute__((ext_vector_type(8)));
typedef float   f32x16 __attribute__((ext_vector_type(16)));
typedef float   f32x4  __attribute__((ext_vector_type(4)));

__device__ __forceinline__ unsigned pack_bf2(float lo, float hi) {
  union { bf16_t b; unsigned short u; } a, c;
  a.b = (bf16_t)lo; c.b = (bf16_t)hi;
  return ((unsigned)c.u << 16) | (unsigned)a.u;
}

__device__ __forceinline__ void gload_lds16(const void* g, void* l) {
  __builtin_amdgcn_global_load_lds(
      (const __attribute__((address_space(1))) void*)g,
      (__attribute__((address_space(3))) void*)l, 16, 0, 0);
}

// ---------------------------------------------------------------------------
// Prep: transpose + cvt weights into per-lane MFMA A-fragment order (bf16).
// w1s[m][kk(16)][t(8)][lane(64)][ii(8)] = bf16(W1[m][n=16kk+8*(lane>>5)+ii][h=32t+(lane&31)])
// w2s[m][kk2(16)][t2(4)][lane(64)][ii(8)] = bf16(W2[m][h=16kk2+8*(lane>>5)+ii][k2=32t2+(lane&31)])
// ---------------------------------------------------------------------------
__global__ __launch_bounds__(256) void prep_weights(
    const float* __restrict__ W1, const float* __restrict__ W2,
    bf16_t* __restrict__ w1s, bf16_t* __restrict__ w2s)
{
  int id = blockIdx.x * 256 + threadIdx.x;
  const int NW1 = M_ * 16 * 8 * 64;   // 24576 groups of 8
  const int NW2 = M_ * 16 * 4 * 64;   // 12288 groups of 8
  if (id < NW1) {
    int lane = id & 63;
    int t    = (id >> 6) & 7;
    int kk   = (id >> 9) & 15;
    int m    = id >> 13;
    int h  = 32 * t + (lane & 31);
    int n0 = 16 * kk + 8 * (lane >> 5);
    bf16x8 v;
#pragma unroll
    for (int ii = 0; ii < 8; ++ii)
      v[ii] = (bf16_t)W1[((size_t)m * N_ + (n0 + ii)) * H1_ + h];
    *reinterpret_cast<bf16x8*>(&w1s[(size_t)id * 8]) = v;
  } else if (id < NW1 + NW2) {
    int j    = id - NW1;
    int lane = j & 63;
    int t2   = (j >> 6) & 3;
    int kk2  = (j >> 8) & 15;
    int m    = j >> 12;
    int k2 = 32 * t2 + (lane & 31);
    int h0 = 16 * kk2 + 8 * (lane >> 5);
    bf16x8 v;
#pragma unroll
    for (int ii = 0; ii < 8; ++ii)
      v[ii] = (bf16_t)W2[((size_t)m * H1_ + (h0 + ii)) * H2_ + k2];
    *reinterpret_cast<bf16x8*>(&w2s[(size_t)j * 8]) = v;
  }
}

// ---------------------------------------------------------------------------
// Main fused kernel. Block = 256 thr = 4 waves; wave owns 32 batch rows per
// unit end-to-end. Block owns 1024 rows x 1 m = 8 units. grid = 768, 1/CU.
// ---------------------------------------------------------------------------
__global__ __launch_bounds__(256, 1) void reservoir_kernel(
    const float* __restrict__ last_flow,
    const float* __restrict__ last_fw,
    const float* __restrict__ runoff,
    const float* __restrict__ b1,
    const float* __restrict__ b2,
    const float* __restrict__ W3,
    const float* __restrict__ b3,
    const bf16_t* __restrict__ w1s,
    const bf16_t* __restrict__ w2s,
    float* __restrict__ out)
{
  // per-wave runoff panel: [32 rows][256 bf16 cols], 16-B granule swizzle
  // phys16 = logical16 ^ (row & 15)
  __shared__ alignas(16) bf16_t sRb[4][8192];   // 4 x 16 KB
  __shared__ alignas(16) bf16_t sW1[3][4096];   // ring-3 of 1-kk panels (8 KB)
  __shared__ alignas(16) bf16_t sW2[32768];     // 64 KB resident (all kk2)
  __shared__ alignas(16) float  sB1[H1_];
  __shared__ alignas(16) float  sB2[H2_];
  __shared__ alignas(16) float  sW3[H2_];       // total 154 KB

  const int tid  = threadIdx.x;
  const int lane = tid & 63;
  const int wv   = tid >> 6;
  const int hi   = lane >> 5;
  const int r    = lane & 31;

  // XCD swizzle: x = XCD (bid%8). The 3 m-partners of a chunk are bids
  // {x+24t, x+24t+8, x+24t+16} -> same XCD, launched adjacently.
  const int x     = blockIdx.x & 7;
  const int s     = blockIdx.x >> 3;       // 0..95
  const int m     = s % 3;
  const int chunk = x * 32 + s / 3;        // 0..255, contiguous per XCD
  const size_t rbase = (size_t)chunk * 1024;

  const bf16_t* w1base = w1s + (size_t)m * 65536;
  const bf16_t* w2base = w2s + (size_t)m * 32768;

  auto stage_w1 = [&](int gkn) {           // stage panel for global-k idx gkn
    int kkp = gkn & 15;
    int sl  = gkn % 3;
#pragma unroll
    for (int c = 0; c < 2; ++c) {
      int chk = wv * 2 + c;                // 8 chunks of 1 KB per panel
      gload_lds16(w1base + (size_t)kkp * 4096 + chk * 512 + lane * 8,
                  &sW1[sl][chk * 512]);
    }
  };

  f32x4 rbuf[32];                          // one unit of runoff, 32 rows x 1 KB
  auto issue_R = [&](int u) {              // sequential 1-KB bursts, own rows
    const float* base = runoff
        + (((size_t)(rbase + u * 128 + wv * 32)) * M_ + m) * N_ + lane * 4;
#pragma unroll
    for (int i = 0; i < 32; ++i)
      rbuf[i] = *reinterpret_cast<const f32x4*>(base + (size_t)i * (M_ * N_));
    __builtin_amdgcn_sched_barrier(0);     // pin issue point
  };

  // ---- prologue: runoff(u0) first (oldest in FIFO), W1(gk0), W2, biases ----
  issue_R(0);
  stage_w1(0);
#pragma unroll
  for (int i = 0; i < 16; ++i) {           // W2: 64 chunks of 1 KB
    int chk = wv * 16 + i;
    gload_lds16(w2base + (size_t)chk * 512 + lane * 8, &sW2[chk * 512]);
  }
  sB1[tid] = b1[m * H1_ + tid];
  if (tid < H2_) { sB2[tid] = b2[m * H2_ + tid]; sW3[tid] = W3[m * H2_ + tid]; }

  for (int u = 0; u < 8; ++u) {
    const int row = (int)rbase + u * 128 + wv * 32 + r;

    // unit start: drain runoff(u) (+ already-landed W1 panel), join waves,
    // then build own bf16 panel (cvt + swizzled ds_write; wave-private).
    asm volatile("s_waitcnt vmcnt(0) lgkmcnt(0)" ::: "memory");
    __builtin_amdgcn_s_barrier();
#pragma unroll
    for (int i = 0; i < 32; ++i) {
      uint2 dd;
      dd.x = pack_bf2(rbuf[i][0], rbuf[i][1]);
      dd.y = pack_bf2(rbuf[i][2], rbuf[i][3]);
      int p8 = lane ^ ((i & 15) << 1);     // 8-B granule swizzle (pairs kept)
      *reinterpret_cast<uint2*>(&sRb[wv][i * 256 + p8 * 4]) = dd;
    }

    // ---------------- Layer 1: a1^T[h][r] ----------------
    f32x16 acc1[8];
#pragma unroll
    for (int t = 0; t < 8; ++t) {
#pragma unroll
      for (int g2 = 0; g2 < 4; ++g2) {
        f32x4 bv = *reinterpret_cast<const f32x4*>(&sB1[32 * t + 8 * g2 + 4 * hi]);
        acc1[t][4 * g2 + 0] = bv[0];
        acc1[t][4 * g2 + 1] = bv[1];
        acc1[t][4 * g2 + 2] = bv[2];
        acc1[t][4 * g2 + 3] = bv[3];
      }
    }
    float rsum = 0.f;

#pragma unroll
    for (int kk = 0; kk < 16; ++kk) {
      const int gk = u * 16 + kk;
      // counted-vmcnt W1 ring: stage gk+1, wait own stage(gk) done (2 newer
      // ops in flight), barrier -> all waves' chunks of panel gk visible.
      if (u < 7 || kk < 15) {
        stage_w1(gk + 1);
        asm volatile("s_waitcnt vmcnt(2)" ::: "memory");
      } else {
        asm volatile("s_waitcnt vmcnt(0)" ::: "memory");
      }
      __builtin_amdgcn_sched_barrier(0);
      __builtin_amdgcn_s_barrier();

      const int sl = gk % 3;
      bf16x8 bfrag = *reinterpret_cast<const bf16x8*>(
          &sRb[wv][r * 256 + (((2 * kk + hi) ^ (r & 15)) * 8)]);
#pragma unroll
      for (int j = 0; j < 8; ++j) rsum += (float)bfrag[j];
#pragma unroll
      for (int t = 0; t < 8; ++t) {
        bf16x8 afrag = *reinterpret_cast<const bf16x8*>(
            &sW1[sl][t * 512 + lane * 8]);
        acc1[t] = __builtin_amdgcn_mfma_f32_32x32x16_bf16(afrag, bfrag, acc1[t], 0, 0, 0);
      }
    }

    // issue next unit's runoff now: after the last counted W1 wait (keeps the
    // vmcnt arithmetic exact), before L2/L3 (~1.5k cyc of cover).
    if (u < 7) issue_R(u + 1);

    // -------- inter-layer: relu + bf16 pack (a1 stays in registers) --------
    unsigned P[8][2][2][2];
#pragma unroll
    for (int t = 0; t < 8; ++t)
#pragma unroll
      for (int q = 0; q < 2; ++q)
#pragma unroll
        for (int v = 0; v < 2; ++v)
#pragma unroll
          for (int ss = 0; ss < 2; ++ss) {
            int e = 8 * q + 4 * v + 2 * ss;
            P[t][q][v][ss] = pack_bf2(fmaxf(acc1[t][e], 0.f),
                                      fmaxf(acc1[t][e + 1], 0.f));
          }

    // ---------------- Layer 2: a2^T[k2][r] (resident W2, no barriers) ------
    f32x16 acc2[4];
#pragma unroll
    for (int t2 = 0; t2 < 4; ++t2) {
#pragma unroll
      for (int g2 = 0; g2 < 4; ++g2) {
        f32x4 bv = *reinterpret_cast<const f32x4*>(&sB2[32 * t2 + 8 * g2 + 4 * hi]);
        acc2[t2][4 * g2 + 0] = bv[0];
        acc2[t2][4 * g2 + 1] = bv[1];
        acc2[t2][4 * g2 + 2] = bv[2];
        acc2[t2][4 * g2 + 3] = bv[3];
      }
    }

#pragma unroll
    for (int kk2 = 0; kk2 < 16; ++kk2) {
      const int t = kk2 >> 1, q = kk2 & 1;
      auto r0 = __builtin_amdgcn_permlane32_swap(P[t][q][0][0], P[t][q][1][0], false, false);
      auto r1 = __builtin_amdgcn_permlane32_swap(P[t][q][0][1], P[t][q][1][1], false, false);
      union { unsigned uu[4]; bf16x8 v; } bb;
      bb.uu[0] = r0[0]; bb.uu[1] = r1[0]; bb.uu[2] = r0[1]; bb.uu[3] = r1[1];
#pragma unroll
      for (int t2 = 0; t2 < 4; ++t2) {
        bf16x8 afrag = *reinterpret_cast<const bf16x8*>(
            &sW2[kk2 * 2048 + t2 * 512 + lane * 8]);
        acc2[t2] = __builtin_amdgcn_mfma_f32_32x32x16_bf16(afrag, bb.v, acc2[t2], 0, 0, 0);
      }
    }

    // ---------------- Layer 3: dot with W3, sigmoid, blend ----------------
    float part = 0.f;
#pragma unroll
    for (int t2 = 0; t2 < 4; ++t2) {
#pragma unroll
      for (int g2 = 0; g2 < 4; ++g2) {
        f32x4 w3v = *reinterpret_cast<const f32x4*>(&sW3[32 * t2 + 8 * g2 + 4 * hi]);
        part += fmaxf(acc2[t2][4 * g2 + 0], 0.f) * w3v[0]
              + fmaxf(acc2[t2][4 * g2 + 1], 0.f) * w3v[1]
              + fmaxf(acc2[t2][4 * g2 + 2], 0.f) * w3v[2]
              + fmaxf(acc2[t2][4 * g2 + 3], 0.f) * w3v[3];
      }
    }
    part += __shfl_xor(part, 32, 64);  // combine k2-mod-8 halves
    rsum += __shfl_xor(rsum, 32, 64);  // combine n-mod-16 halves

    const float xx    = part + b3[m];
    const float ratio = 1.0f / (1.0f + __expf(-xx));
    const size_t oi   = (size_t)row * M_ + m;
    const float fw    = last_fw[oi] + rsum;
    const float lf    = last_flow[oi];
    const float flow  = fw * ratio + lf * (1.0f - ratio);
    if (hi == 0) {
      out[oi]        = fw - flow;   // new_free_water
      out[BM_ + oi]  = flow;        // flow
    }
  }
}

// ---------------------------------------------------------------------------
extern "C" void kernel_launch(void* const* d_in, const int* in_sizes, int n_in,
                              void* d_out, int out_size, void* d_ws, size_t ws_size,
                              hipStream_t stream) {
  const float* last_flow = (const float*)d_in[0];
  const float* last_fw   = (const float*)d_in[1];
  const float* runoff    = (const float*)d_in[2];
  const float* W1 = (const float*)d_in[3];
  const float* b1 = (const float*)d_in[4];
  const float* W2 = (const float*)d_in[5];
  const float* b2 = (const float*)d_in[6];
  const float* W3 = (const float*)d_in[7];
  const float* b3 = (const float*)d_in[8];
  float* out = (float*)d_out;

  bf16_t* w1s = (bf16_t*)d_ws;                    // 3*65536 bf16 = 384 KB
  bf16_t* w2s = w1s + (size_t)M_ * 65536;         // 3*32768 bf16 = 192 KB

  prep_weights<<<144, 256, 0, stream>>>(W1, W2, w1s, w2s);

  reservoir_kernel<<<768, 256, 0, stream>>>(last_flow, last_fw, runoff,
                                            b1, b2, W3, b3, w1s, w2s, out);
}

// Round 5
// 287.375 us; speedup vs baseline: 1.7108x; 1.7108x over previous
//
#include <hip/hip_runtime.h>
#include <hip/hip_bf16.h>

// NonlinearReservoirCell: B=262144 rows, M=3 independent tiny MLPs
//   free_water = last_free_water + sum_n runoff
//   a1 = relu(runoff @ W1 + b1)   (256 -> 256)
//   a2 = relu(a1 @ W2 + b2)       (256 -> 128)
//   ratio = sigmoid(a2 @ W3 + b3) (128 -> 1)
//   flow = fw*ratio + last_flow*(1-ratio);  new_fw = fw - flow
// bf16 MFMA (32x32x16), batch row = lane&31 (swapped orientation).
// R5: EXACT R1/R2 kernel (289 us, 2 blocks/CU) with ONE change: 1D grid,
//     m = bid%3 so the 3 m-partner blocks of each 128-row chunk are
//     launch-adjacent -> temporally co-resident -> their interleaved 1-KB
//     streams consume each 3-KB runoff row in one DRAM page-open window.
//     Pure A/B test of the DRAM page-locality theory.

#define B_TOT 262144
#define M_    3
#define N_    256
#define H1_   256
#define H2_   128
#define BM_   (B_TOT * M_)

typedef __bf16 bf16_t;
typedef __bf16  bf16x8 __attribute__((ext_vector_type(8)));
typedef float   f32x16 __attribute__((ext_vector_type(16)));
typedef float   f32x4  __attribute__((ext_vector_type(4)));

__device__ __forceinline__ unsigned pack_bf2(float lo, float hi) {
  union { bf16_t b; unsigned short u; } a, c;
  a.b = (bf16_t)lo; c.b = (bf16_t)hi;
  return ((unsigned)c.u << 16) | (unsigned)a.u;
}

__device__ __forceinline__ void gload_lds16(const void* g, void* l) {
  __builtin_amdgcn_global_load_lds(
      (const __attribute__((address_space(1))) void*)g,
      (__attribute__((address_space(3))) void*)l, 16, 0, 0);
}

// ---------------------------------------------------------------------------
// Prep: transpose + cvt weights into per-lane MFMA A-fragment order (bf16).
// w1s[m][kk(16)][t(8)][lane(64)][ii(8)] = bf16(W1[m][n=16kk+8*(lane>>5)+ii][h=32t+(lane&31)])
// w2s[m][kk2(16)][t2(4)][lane(64)][ii(8)] = bf16(W2[m][h=16kk2+8*(lane>>5)+ii][k2=32t2+(lane&31)])
// ---------------------------------------------------------------------------
__global__ __launch_bounds__(256) void prep_weights(
    const float* __restrict__ W1, const float* __restrict__ W2,
    bf16_t* __restrict__ w1s, bf16_t* __restrict__ w2s)
{
  int id = blockIdx.x * 256 + threadIdx.x;
  const int NW1 = M_ * 16 * 8 * 64;   // 24576 groups of 8
  const int NW2 = M_ * 16 * 4 * 64;   // 12288 groups of 8
  if (id < NW1) {
    int lane = id & 63;
    int t    = (id >> 6) & 7;
    int kk   = (id >> 9) & 15;
    int m    = id >> 13;
    int h  = 32 * t + (lane & 31);
    int n0 = 16 * kk + 8 * (lane >> 5);
    bf16x8 v;
#pragma unroll
    for (int ii = 0; ii < 8; ++ii)
      v[ii] = (bf16_t)W1[((size_t)m * N_ + (n0 + ii)) * H1_ + h];
    *reinterpret_cast<bf16x8*>(&w1s[(size_t)id * 8]) = v;
  } else if (id < NW1 + NW2) {
    int j    = id - NW1;
    int lane = j & 63;
    int t2   = (j >> 6) & 3;
    int kk2  = (j >> 8) & 15;
    int m    = j >> 12;
    int k2 = 32 * t2 + (lane & 31);
    int h0 = 16 * kk2 + 8 * (lane >> 5);
    bf16x8 v;
#pragma unroll
    for (int ii = 0; ii < 8; ++ii)
      v[ii] = (bf16_t)W2[((size_t)m * H1_ + (h0 + ii)) * H2_ + k2];
    *reinterpret_cast<bf16x8*>(&w2s[(size_t)j * 8]) = v;
  }
}

// ---------------------------------------------------------------------------
// Main fused kernel. Block = 256 thr = 4 waves; wave owns 32 batch rows.
// grid = 6144 1D; m = bid%3 (m-partners launch-adjacent), chunk = bid/3.
// ---------------------------------------------------------------------------
__global__ __launch_bounds__(256, 2) void reservoir_kernel(
    const float* __restrict__ last_flow,
    const float* __restrict__ last_fw,
    const float* __restrict__ runoff,
    const float* __restrict__ b1,
    const float* __restrict__ b2,
    const float* __restrict__ W3,
    const float* __restrict__ b3,
    const bf16_t* __restrict__ w1s,
    const bf16_t* __restrict__ w2s,
    float* __restrict__ out)
{
  // Runoff panel: [128 rows][32 floats], XOR-swizzled in 16-B granules:
  //   phys_granule = logical_granule ^ (row & 7)
  __shared__ alignas(16) float  sR[2][128 * 32];   // 2 x 16 KB
  __shared__ alignas(16) bf16_t sW1[2][8192];      // 2 x 16 KB (2 kk-panels)
  __shared__ alignas(16) bf16_t sW2[2][2048];      // 2 x 4 KB
  __shared__ alignas(16) float  sB1[H1_];
  __shared__ alignas(16) float  sB2[H2_];
  __shared__ alignas(16) float  sW3[H2_];

  const int tid  = threadIdx.x;
  const int lane = tid & 63;
  const int wv   = tid >> 6;
  const int hi   = lane >> 5;
  const int r    = lane & 31;
  const int r7   = r & 7;

  // R5 change: m-partners adjacent in dispatch order
  const int bidx  = blockIdx.x;        // 0..6143
  const int m     = bidx % 3;
  const int chunk = bidx / 3;          // 0..2047
  const int row0  = chunk * 128;
  const int row   = row0 + wv * 32 + r;

  // staging-lane decomposition for sR: 8 rows x 8 granules per instruction
  const int l3 = lane >> 3;          // row within 8-row slab
  const int gsw = (lane & 7) ^ l3;   // logical granule feeding phys slot lane&7

  const bf16_t* w1base = w1s + (size_t)m * 65536;
  const bf16_t* w2base = w2s + (size_t)m * 32768;

  auto stage_R = [&](int g, int buf) {     // panel g: cols 32g..32g+31
#pragma unroll
    for (int c = 0; c < 4; ++c) {
      int slab = wv * 4 + c;               // 16 slabs of 8 rows
      const float* src = runoff
          + ((size_t)(row0 + slab * 8 + l3) * M_ + m) * N_ + 32 * g + 4 * gsw;
      gload_lds16(src, &sR[buf][slab * 256]);
    }
  };
  auto stage_w1g = [&](int g, int buf) {   // panels 2g,2g+1: 16 KB
#pragma unroll
    for (int c = 0; c < 4; ++c) {
      int chnk = wv * 4 + c;               // 16 chunks of 1 KB
      gload_lds16(w1base + (size_t)g * 8192 + chnk * 512 + lane * 8,
                  &sW1[buf][chnk * 512]);
    }
  };
  auto stage_w2 = [&](int kk2, int buf) {
    gload_lds16(w2base + (size_t)kk2 * 2048 + wv * 512 + lane * 8,
                &sW2[buf][wv * 512]);
  };

  // prologue: biases, first runoff panel, first W1 group
  sB1[tid] = b1[m * H1_ + tid];
  if (tid < H2_) { sB2[tid] = b2[m * H2_ + tid]; sW3[tid] = W3[m * H2_ + tid]; }
  stage_R(0, 0);
  stage_w1g(0, 0);
  __syncthreads();

  // ---------------- Layer 1: a1^T[h][r] ----------------
  f32x16 acc1[8];
#pragma unroll
  for (int t = 0; t < 8; ++t) {
#pragma unroll
    for (int g2 = 0; g2 < 4; ++g2) {
      f32x4 bv = *reinterpret_cast<const f32x4*>(&sB1[32 * t + 8 * g2 + 4 * hi]);
      acc1[t][4 * g2 + 0] = bv[0];
      acc1[t][4 * g2 + 1] = bv[1];
      acc1[t][4 * g2 + 2] = bv[2];
      acc1[t][4 * g2 + 3] = bv[3];
    }
  }

  float rsum = 0.f;

#pragma unroll
  for (int g = 0; g < 8; ++g) {
    const int cb = g & 1;
    if (g < 7) { stage_R(g + 1, cb ^ 1); stage_w1g(g + 1, cb ^ 1); }
    else       { stage_w2(0, 0); }   // prefetch first W2 panel

#pragma unroll
    for (int q = 0; q < 2; ++q) {    // kk = 2g + q
      const float* rb = &sR[cb][(wv * 32 + r) * 32];
      f32x4 qa = *reinterpret_cast<const f32x4*>(&rb[((4 * q + 2 * hi + 0) ^ r7) * 4]);
      f32x4 qb = *reinterpret_cast<const f32x4*>(&rb[((4 * q + 2 * hi + 1) ^ r7) * 4]);
      rsum += qa[0] + qa[1] + qa[2] + qa[3] + qb[0] + qb[1] + qb[2] + qb[3];
      bf16x8 bfrag;
      bfrag[0] = (bf16_t)qa[0]; bfrag[1] = (bf16_t)qa[1];
      bfrag[2] = (bf16_t)qa[2]; bfrag[3] = (bf16_t)qa[3];
      bfrag[4] = (bf16_t)qb[0]; bfrag[5] = (bf16_t)qb[1];
      bfrag[6] = (bf16_t)qb[2]; bfrag[7] = (bf16_t)qb[3];

#pragma unroll
      for (int t = 0; t < 8; ++t) {
        bf16x8 afrag = *reinterpret_cast<const bf16x8*>(
            &sW1[cb][q * 4096 + t * 512 + lane * 8]);
        acc1[t] = __builtin_amdgcn_mfma_f32_32x32x16_bf16(afrag, bfrag, acc1[t], 0, 0, 0);
      }
    }
    __syncthreads();
  }

  // -------- inter-layer: relu + bf16 pack (a1 stays in registers) --------
  unsigned P[8][2][2][2];
#pragma unroll
  for (int t = 0; t < 8; ++t)
#pragma unroll
    for (int q = 0; q < 2; ++q)
#pragma unroll
      for (int v = 0; v < 2; ++v)
#pragma unroll
        for (int s = 0; s < 2; ++s) {
          int e = 8 * q + 4 * v + 2 * s;
          P[t][q][v][s] = pack_bf2(fmaxf(acc1[t][e], 0.f),
                                   fmaxf(acc1[t][e + 1], 0.f));
        }

  // ---------------- Layer 2: a2^T[k2][r] ----------------
  f32x16 acc2[4];
#pragma unroll
  for (int t2 = 0; t2 < 4; ++t2) {
#pragma unroll
    for (int g2 = 0; g2 < 4; ++g2) {
      f32x4 bv = *reinterpret_cast<const f32x4*>(&sB2[32 * t2 + 8 * g2 + 4 * hi]);
      acc2[t2][4 * g2 + 0] = bv[0];
      acc2[t2][4 * g2 + 1] = bv[1];
      acc2[t2][4 * g2 + 2] = bv[2];
      acc2[t2][4 * g2 + 3] = bv[3];
    }
  }

#pragma unroll
  for (int kk2 = 0; kk2 < 16; ++kk2) {
    const int cb = kk2 & 1;
    if (kk2 < 15) stage_w2(kk2 + 1, cb ^ 1);
    const int t = kk2 >> 1, q = kk2 & 1;

    // B2-frag via 2 permlane32_swap
    auto r0 = __builtin_amdgcn_permlane32_swap(P[t][q][0][0], P[t][q][1][0], false, false);
    auto r1 = __builtin_amdgcn_permlane32_swap(P[t][q][0][1], P[t][q][1][1], false, false);
    union { unsigned u[4]; bf16x8 v; } bb;
    bb.u[0] = r0[0]; bb.u[1] = r1[0]; bb.u[2] = r0[1]; bb.u[3] = r1[1];

#pragma unroll
    for (int t2 = 0; t2 < 4; ++t2) {
      bf16x8 afrag = *reinterpret_cast<const bf16x8*>(
          &sW2[cb][t2 * 512 + lane * 8]);
      acc2[t2] = __builtin_amdgcn_mfma_f32_32x32x16_bf16(afrag, bb.v, acc2[t2], 0, 0, 0);
    }
    __syncthreads();
  }

  // ---------------- Layer 3: dot with W3, sigmoid, blend ----------------
  float part = 0.f;
#pragma unroll
  for (int t2 = 0; t2 < 4; ++t2) {
#pragma unroll
    for (int g2 = 0; g2 < 4; ++g2) {
      f32x4 w3v = *reinterpret_cast<const f32x4*>(&sW3[32 * t2 + 8 * g2 + 4 * hi]);
      part += fmaxf(acc2[t2][4 * g2 + 0], 0.f) * w3v[0]
            + fmaxf(acc2[t2][4 * g2 + 1], 0.f) * w3v[1]
            + fmaxf(acc2[t2][4 * g2 + 2], 0.f) * w3v[2]
            + fmaxf(acc2[t2][4 * g2 + 3], 0.f) * w3v[3];
    }
  }
  part += __shfl_xor(part, 32, 64);  // combine k2-mod-8 halves
  rsum += __shfl_xor(rsum, 32, 64);  // combine n-mod-16 halves

  const float x     = part + b3[m];
  const float ratio = 1.0f / (1.0f + __expf(-x));
  const size_t oi   = (size_t)row * M_ + m;
  const float fw    = last_fw[oi] + rsum;
  const float lf    = last_flow[oi];
  const float flow  = fw * ratio + lf * (1.0f - ratio);
  if (hi == 0) {
    out[oi]        = fw - flow;   // new_free_water
    out[BM_ + oi]  = flow;        // flow
  }
}

// ---------------------------------------------------------------------------
extern "C" void kernel_launch(void* const* d_in, const int* in_sizes, int n_in,
                              void* d_out, int out_size, void* d_ws, size_t ws_size,
                              hipStream_t stream) {
  const float* last_flow = (const float*)d_in[0];
  const float* last_fw   = (const float*)d_in[1];
  const float* runoff    = (const float*)d_in[2];
  const float* W1 = (const float*)d_in[3];
  const float* b1 = (const float*)d_in[4];
  const float* W2 = (const float*)d_in[5];
  const float* b2 = (const float*)d_in[6];
  const float* W3 = (const float*)d_in[7];
  const float* b3 = (const float*)d_in[8];
  float* out = (float*)d_out;

  bf16_t* w1s = (bf16_t*)d_ws;                    // 3*65536 bf16 = 384 KB
  bf16_t* w2s = w1s + (size_t)M_ * 65536;         // 3*32768 bf16 = 192 KB

  prep_weights<<<144, 256, 0, stream>>>(W1, W2, w1s, w2s);

  reservoir_kernel<<<6144, 256, 0, stream>>>(last_flow, last_fw, runoff,
                                             b1, b2, W3, b3, w1s, w2s, out);
}